// Round 13
// baseline (3430.746 us; speedup 1.0000x reference)
//
#include <hip/hip_runtime.h>

typedef _Float16 half_t;
typedef _Float16 f16x8 __attribute__((ext_vector_type(8)));
typedef _Float16 f16x4 __attribute__((ext_vector_type(4)));
typedef float f32x4 __attribute__((ext_vector_type(4)));

#define BB 4
#define NNODE 24
#define NLAYER 64
#define SCALE_QK 0.0625f

// ---- workspace layout (float offsets) ----
// Region-end audit (floats): C 0+1024=1024 | N 1024+24576=25600 |
// NACC 25600+2*24576=74752 | E 74752+589824=664576 | EACC 664576+2*589824=1844224 |
// AE16 1844224+294912=2139136 | AN16 2139136+12288=2151424 | WTF 2151424+2129920=4281344
#define WS_C     0               // [4][256] f32
#define WS_N     1024            // [96][256] f32 (embed n(0))
#define WS_NACC  25600           // 2 x [96][256] f32 (parity = layer&1)
#define NACC_STRIDE 24576
#define WS_E     74752           // [2304][256] f32 (embed e(0))
#define WS_EACC  664576          // 2 x [2304][256] f32 (parity = layer&1; LN1e-init + ME2 atomics)
#define EACC_STRIDE 589824
#define WS_AE16  1844224         // [2304][256] f16 (294912 floats)
#define WS_AN16  2139136         // [96][256] f16 (12288 floats, ends 2151424)
#define WS_WTF   2151424         // f16 weight region (FIXED: was 2145280, overlapping WS_AN16)
#define SLOT_F16 1376256
#define OFF_QKVT 0               // [768][256]
#define OFF_NOT  196608          // [256][256]
#define OFF_EOT  262144          // [256][256]
#define OFF_MN1T 327680          // [1024][256]
#define OFF_MN2T 589824          // [256][1024]
#define OFF_ME1T 851968          // [1024][256]
#define OFF_ME2T 1114112         // [256][1024]
#define OFF_INE2T  (3*SLOT_F16)          // [256][256]
#define OFF_OUTE1T (3*SLOT_F16 + 65536)  // [256][256]

struct Params {
  const float *nodes, *edges; const int* conds;
  const float *inN_w1,*inN_b1,*inN_w2,*inN_b2;
  const float *inE_w1,*inE_b1,*inE_w2,*inE_b2;
  const float *inC_w1,*inC_b1,*inC_w2,*inC_b2;
  const float *qkv_w,*qkv_b,*no_w,*no_b,*eo_w,*eo_b;
  const float *ln1n_g,*ln1n_b,*ln1e_g,*ln1e_b;
  const float *mn_w1,*mn_b1,*mn_w2,*mn_b2,*me_w1,*me_b1,*me_w2,*me_b2;
  const float *ln2n_g,*ln2n_b,*ln2e_g,*ln2e_b;
  const float *outN_w1,*outN_b1,*outN_w2,*outN_b2,*outE_w1,*outE_b1,*outE_w2,*outE_b2;
  float* ws; float* out;
};

// ---- register-stationary MFMA GEMM ----
template<int NT, int KS, int MT, int LDAH>
__device__ __forceinline__ void gemm_rs_acc(const half_t* __restrict__ WT, int ldb,
                                            const char* __restrict__ A,
                                            f32x4 (&acc)[NT][MT]) {
  const int lane = threadIdx.x & 63;
  const int wv = threadIdx.x >> 6;
  const int l15 = lane & 15;
  const int kg = lane >> 4;
  f16x8 b[NT][KS];
#pragma unroll
  for (int nt = 0; nt < NT; ++nt) {
    const int col = (nt * 8 + wv) * 16 + l15;
#pragma unroll
    for (int ks = 0; ks < KS; ++ks)
      b[nt][ks] = *(const f16x8*)(WT + (size_t)col * ldb + ks * 32 + kg * 8);
  }
#pragma unroll
  for (int m = 0; m < MT; ++m) {
    f16x8 a[KS];
    const int row = m * 16 + l15;
#pragma unroll
    for (int ks = 0; ks < KS; ++ks)
      a[ks] = *(const f16x8*)(A + row * (LDAH * 2) + (((ks * 32 + kg * 8) * 2) ^ ((row & 7) << 4)));
#pragma unroll
    for (int ks = 0; ks < KS; ++ks)
#pragma unroll
      for (int nt = 0; nt < NT; ++nt)
        acc[nt][m] = __builtin_amdgcn_mfma_f32_16x16x32_f16(a[ks], b[nt][ks], acc[nt][m], 0, 0, 0);
  }
}

template<int NT, int KS, int MT, int LDAH, typename EPI>
__device__ __forceinline__ void gemm_rs(const half_t* __restrict__ WT, int ldb,
                                        const char* __restrict__ A, EPI epi) {
  f32x4 acc[NT][MT];
#pragma unroll
  for (int nt = 0; nt < NT; ++nt)
#pragma unroll
    for (int m = 0; m < MT; ++m) {
      f32x4 z = {0.f, 0.f, 0.f, 0.f};
      acc[nt][m] = z;
    }
  gemm_rs_acc<NT, KS, MT, LDAH>(WT, ldb, A, acc);
#pragma unroll
  for (int nt = 0; nt < NT; ++nt)
#pragma unroll
    for (int m = 0; m < MT; ++m)
      epi(nt, m, acc[nt][m]);
}

// ---- NT=1 variant with caller-preloaded B fragments ----
template<int KS>
__device__ __forceinline__ void load_b1(const half_t* __restrict__ WT, int ldb, f16x8 (&b)[KS]) {
  const int lane = threadIdx.x & 63, wvq = threadIdx.x >> 6;
  const int col = wvq * 16 + (lane & 15), kg = lane >> 4;
#pragma unroll
  for (int ks = 0; ks < KS; ++ks)
    b[ks] = *(const f16x8*)(WT + (size_t)col * ldb + ks * 32 + kg * 8);
}

template<int KS, int MT, int LDAH, typename EPI>
__device__ __forceinline__ void gemm_rs_preb(const f16x8 (&b)[KS], const char* __restrict__ A, EPI epi) {
  const int lane = threadIdx.x & 63;
  const int l15 = lane & 15, kg = lane >> 4;
  f32x4 acc[MT];
#pragma unroll
  for (int m = 0; m < MT; ++m) { f32x4 z = {0.f,0.f,0.f,0.f}; acc[m] = z; }
#pragma unroll
  for (int m = 0; m < MT; ++m) {
    const int row = m * 16 + l15;
    f16x8 a[KS];
#pragma unroll
    for (int ks = 0; ks < KS; ++ks)
      a[ks] = *(const f16x8*)(A + row * (LDAH * 2) + (((ks * 32 + kg * 8) * 2) ^ ((row & 7) << 4)));
#pragma unroll
    for (int ks = 0; ks < KS; ++ks)
      acc[m] = __builtin_amdgcn_mfma_f32_16x16x32_f16(a[ks], b[ks], acc[m], 0, 0, 0);
  }
#pragma unroll
  for (int m = 0; m < MT; ++m) epi(m, acc[m]);
}

// ---- legacy batched gemm (embed/out kernels) ----
template<int NTW, int KT, int MT, int LDA, int LDB, typename EPI>
__device__ __forceinline__ void run_gemm_s(const half_t* __restrict__ WT,
                                           const char* __restrict__ A,
                                           EPI epi) {
  const int lane = threadIdx.x & 63;
  const int wv = threadIdx.x >> 6;
  const int l15 = lane & 15;
  const int kg = lane >> 4;
  constexpr int NC = KT / 8;
  constexpr int TC = NC * NTW;
  f16x8 bb[2][8];
  auto ldb = [&](int c, int w) {
    const int kc = c / NTW, n = c % NTW;
    const half_t* bp = WT + (size_t)((n * 8 + wv) * 16 + l15) * LDB + kc * 256 + kg * 8;
#pragma unroll
    for (int q = 0; q < 8; ++q) bb[w][q] = *(const f16x8*)(bp + q * 32);
  };
  f32x4 acc[NTW][MT];
#pragma unroll
  for (int n = 0; n < NTW; ++n)
#pragma unroll
    for (int m = 0; m < MT; ++m) {
      f32x4 z = {0.f, 0.f, 0.f, 0.f};
      acc[n][m] = z;
    }
  ldb(0, 0);
#pragma unroll
  for (int kc = 0; kc < NC; ++kc) {
    f16x8 a[8][MT];
#pragma unroll
    for (int q = 0; q < 8; ++q) {
      const int k0 = (kc * 8 + q) * 32 + kg * 8;
#pragma unroll
      for (int m = 0; m < MT; ++m) {
        const int row = m * 16 + l15;
        a[q][m] = *(const f16x8*)(A + row * (LDA * 2) + ((k0 * 2) ^ ((row & 7) << 4)));
      }
    }
#pragma unroll
    for (int n = 0; n < NTW; ++n) {
      const int c = kc * NTW + n;
      if (c + 1 < TC) ldb(c + 1, (c + 1) & 1);
#pragma unroll
      for (int q = 0; q < 8; ++q)
#pragma unroll
        for (int m = 0; m < MT; ++m)
          acc[n][m] = __builtin_amdgcn_mfma_f32_16x16x32_f16(a[q][m], bb[c & 1][q], acc[n][m], 0, 0, 0);
    }
  }
#pragma unroll
  for (int n = 0; n < NTW; ++n) epi(n, acc[n]);
}

// ---- 64x64 transpose+convert fp32 -> f16 tile ----
__device__ void conv_matrix_tile(const float* __restrict__ src, half_t* __restrict__ dst,
                                 int K, int Nn, int tk, int tn, char* smem) {
  float* tl = (float*)smem;  // [64][65]
  const int t = threadIdx.x;
  const int c = t & 63;
  const int r0 = t >> 6;
  for (int r = r0; r < 64; r += 8)
    tl[r * 65 + c] = src[(size_t)(tk * 64 + r) * Nn + tn * 64 + c];
  __syncthreads();
  for (int r = r0; r < 64; r += 8)
    dst[(size_t)(tn * 64 + r) * K + tk * 64 + c] = (half_t)tl[c * 65 + r];
  __syncthreads();
}

__device__ void conv_layer_tile(const Params& p, half_t* slot, int lw, int tile, char* smem) {
  if (tile < 48)       { conv_matrix_tile(p.qkv_w + (size_t)lw*196608, slot+OFF_QKVT, 256, 768, tile & 3, tile >> 2, smem); }
  else if (tile < 64)  { int t2 = tile-48;  conv_matrix_tile(p.no_w  + (size_t)lw*65536,  slot+OFF_NOT,  256, 256, t2 & 3,  t2 >> 2, smem); }
  else if (tile < 80)  { int t2 = tile-64;  conv_matrix_tile(p.eo_w  + (size_t)lw*65536,  slot+OFF_EOT,  256, 256, t2 & 3,  t2 >> 2, smem); }
  else if (tile < 144) { int t2 = tile-80;  conv_matrix_tile(p.mn_w1 + (size_t)lw*262144, slot+OFF_MN1T, 256, 1024, t2 & 3, t2 >> 2, smem); }
  else if (tile < 208) { int t2 = tile-144; conv_matrix_tile(p.mn_w2 + (size_t)lw*262144, slot+OFF_MN2T, 1024, 256, t2 & 15, t2 >> 4, smem); }
  else if (tile < 272) { int t2 = tile-208; conv_matrix_tile(p.me_w1 + (size_t)lw*262144, slot+OFF_ME1T, 256, 1024, t2 & 3, t2 >> 2, smem); }
  else                 { int t2 = tile-272; conv_matrix_tile(p.me_w2 + (size_t)lw*262144, slot+OFF_ME2T, 1024, 256, t2 & 15, t2 >> 4, smem); }
}

// ================= embed A =================
__global__ __launch_bounds__(512, 2) void k_embedA(Params p) {
  __shared__ __align__(16) char smem[17024];
  const int bid = blockIdx.x, tid = threadIdx.x;
  float* ws = p.ws;
  half_t* wt = (half_t*)(ws + WS_WTF);
  if (bid < 4) {
    const int b = bid;
    const int cond = p.conds[b];
    float* t1 = (float*)smem;
    if (tid < 256) t1[tid] = fmaxf(p.inC_w1[(size_t)cond * 256 + tid] + p.inC_b1[tid], 0.f);
    __syncthreads();
    if (tid < 256) {
      float s = p.inC_b2[tid];
      for (int k = 0; k < 256; ++k) s += t1[k] * p.inC_w2[(size_t)k * 256 + tid];
      ws[WS_C + b * 256 + tid] = fmaxf(s, 0.f);
    }
  } else {
    for (int job = bid - 4; job < 704; job += 128) {
      if (job < 336)      conv_layer_tile(p, wt, 0, job, smem);
      else if (job < 672) conv_layer_tile(p, wt + SLOT_F16, 1, job - 336, smem);
      else if (job < 688) { int t2 = job - 672; conv_matrix_tile(p.inE_w2,  wt + OFF_INE2T,  256, 256, t2 & 3, t2 >> 2, smem); }
      else                { int t2 = job - 688; conv_matrix_tile(p.outE_w1, wt + OFF_OUTE1T, 256, 256, t2 & 3, t2 >> 2, smem); }
    }
  }
}

// ================= embed B: edge embed (MFMA), node embed =================
__global__ __launch_bounds__(512, 2) void k_embedB(Params p) {
  __shared__ __align__(16) char smem[24640];
  const int bid = blockIdx.x, tid = threadIdx.x;
  const int lane = tid & 63, wv = tid >> 6, l15 = lane & 15, kg = lane >> 4;
  float* ws = p.ws;
  half_t* wt = (half_t*)(ws + WS_WTF);
  float* e0 = ws + WS_E;
  float* n0 = ws + WS_N;
  if (bid < 96) {
    const int b = bid / NNODE, i = bid % NNODE;
    float* eb = (float*)smem;        // [24][12]
    char* t16 = smem + 2048;         // [32][512] f16
    for (int idx = tid; idx < 24 * 12; idx += 512)
      eb[idx] = p.edges[((size_t)(b * NNODE + i) * NNODE + idx / 12) * 12 + idx % 12];
    __syncthreads();
    for (int idx = tid; idx < 32 * 32; idx += 512) {
      int r = idx >> 5, kb = idx & 31, k0 = kb * 8;
      f16x8 v;
#pragma unroll
      for (int j = 0; j < 8; ++j) v[j] = (half_t)0.f;
      if (r < NNODE) {
#pragma unroll
        for (int j = 0; j < 8; ++j) {
          int col = k0 + j;
          float s = p.inE_b1[col];
          for (int kk = 0; kk < 12; ++kk) s += eb[r * 12 + kk] * p.inE_w1[kk * 256 + col];
          v[j] = (half_t)fmaxf(s, 0.f);
        }
      }
      *(f16x8*)(t16 + r * 512 + ((k0 * 2) ^ ((r & 7) << 4))) = v;
    }
    __syncthreads();
    run_gemm_s<2, 8, 2, 256, 256>(wt + OFF_INE2T, t16,
      [&](int n, f32x4 (&accn)[2]) {
        const int col = (n * 8 + wv) * 16 + l15;
        const float bcol = p.inE_b2[col];
#pragma unroll
        for (int m = 0; m < 2; ++m)
#pragma unroll
          for (int r4 = 0; r4 < 4; ++r4) {
            const int row = m * 16 + kg * 4 + r4;
            if (row < NNODE)
              e0[((size_t)(b * NNODE + i) * NNODE + row) * 256 + col] = fmaxf(accn[m][r4] + bcol, 0.f);
          }
      });
  } else {
    const int nb = bid - 96, b = nb >> 1, hf = nb & 1, i0 = hf * 12;
    float* nd = (float*)smem;            // [12][16]
    float* t1 = (float*)(smem + 1024);   // [12][257]
    for (int idx = tid; idx < 12 * 13; idx += 512)
      nd[(idx / 13) * 16 + (idx % 13)] = p.nodes[(size_t)(b * NNODE + i0 + idx / 13) * 13 + idx % 13];
    __syncthreads();
    for (int idx = tid; idx < 12 * 256; idx += 512) {
      int r = idx >> 8, col = idx & 255;
      float s = p.inN_b1[col];
      for (int kk = 0; kk < 13; ++kk) s += nd[r * 16 + kk] * p.inN_w1[kk * 256 + col];
      t1[r * 257 + col] = fmaxf(s, 0.f);
    }
    __syncthreads();
    {
      int col = tid & 255, rh = tid >> 8;
      float a6[6] = {0.f, 0.f, 0.f, 0.f, 0.f, 0.f};
      for (int k = 0; k < 256; ++k) {
        float w = p.inN_w2[(size_t)k * 256 + col];
#pragma unroll
        for (int r = 0; r < 6; ++r) a6[r] += t1[(rh * 6 + r) * 257 + k] * w;
      }
#pragma unroll
      for (int r = 0; r < 6; ++r) {
        int row = rh * 6 + r;
        n0[(size_t)(b * NNODE + i0 + row) * 256 + col] = fmaxf(a6[r] + p.inN_b2[col], 0.f);
      }
    }
  }
}

// ===== KA: LN2n-recon + QKV + LN2e(eacc) + attn + EO + LN1e->eacc-init + NO + LN1n =====
__global__ __launch_bounds__(512, 2) void k_attn(Params p, int lyr) {
  __shared__ __align__(16) char smem[139488];
  const int bid = blockIdx.x, tid = threadIdx.x;
  const int lane = tid & 63, wv = tid >> 6, l15 = lane & 15, kg = lane >> 4;
  float* ws = p.ws;
  half_t* wt = (half_t*)(ws + WS_WTF);
  const half_t* slot = wt + (size_t)(lyr % 3) * SLOT_F16;

  if (bid >= 96) {
    if (lyr + 2 < NLAYER) {
      half_t* dslot = wt + (size_t)((lyr + 2) % 3) * SLOT_F16;
      for (int tile = bid - 96; tile < 336; tile += 126)
        conv_layer_tile(p, dslot, lyr + 2, tile, smem);
    }
    return;
  }
  const int b = bid / NNODE, i = bid % NNODE;
  const size_t rowbase = (size_t)(b * NNODE + i) * NNODE;
  char* nc16 = smem;                        // [32][512]
  half_t* qkv16 = (half_t*)(smem + 16384);  // [32][768]
  char* ne5 = smem + 65536;                 // [32][512]
  float* e32 = (float*)(smem + 81920);      // [24][260]
  float* psum = (float*)(smem + 106880);    // [24][32]
  float* sc = (float*)(smem + 109952);      // [24][8]
  float* wvl = (float*)(smem + 110720);     // [256]
  float* ni = (float*)(smem + 111744);      // [256]
  float* anr = (float*)(smem + 112768);     // [2][256]
  float* aef = (float*)(smem + 114816);     // [24][257]
  half_t* ae16g = (half_t*)(ws + WS_AE16);
  const float* eacc_in = ws + WS_EACC + ((lyr + 1) & 1) * EACC_STRIDE;
  float* eacc_out = ws + WS_EACC + (lyr & 1) * EACC_STRIDE;
  const float* nacc_in = ws + WS_NACC + ((lyr + 1) & 1) * NACC_STRIDE;
  float* nacc_out = ws + WS_NACC + (lyr & 1) * NACC_STRIDE;
  const float* cb = ws + WS_C + b * 256;

  // ---- phase 1: n(l) rows of batch b (LN2n recon for l>=1) -> nc16 (+c), ni
  for (int r = wv; r < 32; r += 8) {
    const int c = lane * 4;
    f16x4 hv;
    if (r < NNODE) {
      f32x4 y;
      if (lyr == 0) {
        y = *(const f32x4*)(ws + WS_N + (size_t)(b * NNODE + r) * 256 + c);
      } else {
        f32x4 x = *(const f32x4*)(nacc_in + (size_t)(b * NNODE + r) * 256 + c);
        float s = x[0] + x[1] + x[2] + x[3];
        float s2 = x[0]*x[0] + x[1]*x[1] + x[2]*x[2] + x[3]*x[3];
#pragma unroll
        for (int off = 32; off; off >>= 1) { s += __shfl_xor(s, off); s2 += __shfl_xor(s2, off); }
        float mean = s * (1.f / 256.f);
        float rstd = rsqrtf(s2 * (1.f / 256.f) - mean * mean + 1e-5f);
        const float* g = p.ln2n_g + (size_t)(lyr - 1) * 256;
        const float* bv = p.ln2n_b + (size_t)(lyr - 1) * 256;
#pragma unroll
        for (int j = 0; j < 4; ++j) y[j] = (x[j] - mean) * rstd * g[c + j] + bv[c + j];
      }
      if (r == i) *(f32x4*)(ni + c) = y;
#pragma unroll
      for (int j = 0; j < 4; ++j) hv[j] = (half_t)(y[j] + cb[c + j]);
    } else {
#pragma unroll
      for (int j = 0; j < 4; ++j) hv[j] = (half_t)0.f;
    }
    *(f16x4*)(nc16 + r * 512 + ((lane * 8) ^ ((r & 7) << 4))) = hv;
  }
  __syncthreads();
  // ---- phase 2: QKV gemm (3 x NT=2)
  {
    const float* qb = p.qkv_b + (size_t)lyr * 768;
#pragma unroll
    for (int nn = 0; nn < 3; ++nn) {
      gemm_rs<2, 8, 2, 256>(slot + OFF_QKVT + (size_t)(nn * 256) * 256, 256, nc16,
        [&](int nt, int m, f32x4 v) {
          const int gcol = nn * 256 + (nt * 8 + wv) * 16 + l15;
          const float bc = qb[gcol];
#pragma unroll
          for (int r4 = 0; r4 < 4; ++r4) {
            const int row = m * 16 + kg * 4 + r4;
            qkv16[(size_t)row * 768 + gcol] = (half_t)(v[r4] + bc);
          }
        });
    }
  }
  __syncthreads();
  // ---- phase 3: LN2e from eacc (2 loads) + scores -> ne5, e32, psum
  for (int idx = tid; idx < 32 * 32; idx += 512) {
    int r = idx >> 5, kb = idx & 31, k0 = kb * 8;
    f16x8 v;
#pragma unroll
    for (int j = 0; j < 8; ++j) v[j] = (half_t)0.f;
    if (r < NNODE) {
      const size_t row = rowbase + r;
      float x[8];
      if (lyr == 0) {
        const f32x4 a = *(const f32x4*)(ws + WS_E + row * 256 + k0);
        const f32x4 b4 = *(const f32x4*)(ws + WS_E + row * 256 + k0 + 4);
#pragma unroll
        for (int j = 0; j < 4; ++j) { x[j] = a[j]; x[4 + j] = b4[j]; }
      } else {
        const f32x4 a = *(const f32x4*)(eacc_in + row * 256 + k0);
        const f32x4 b4 = *(const f32x4*)(eacc_in + row * 256 + k0 + 4);
#pragma unroll
        for (int j = 0; j < 4; ++j) { x[j] = a[j]; x[4 + j] = b4[j]; }
        float s = 0.f, s2 = 0.f;
#pragma unroll
        for (int j = 0; j < 8; ++j) { s += x[j]; s2 += x[j] * x[j]; }
#pragma unroll
        for (int off = 16; off; off >>= 1) { s += __shfl_xor(s, off); s2 += __shfl_xor(s2, off); }
        float mean = s * (1.f / 256.f);
        float rstd = rsqrtf(s2 * (1.f / 256.f) - mean * mean + 1e-5f);
        const float* g = p.ln2e_g + (size_t)(lyr - 1) * 256;
        const float* bv = p.ln2e_b + (size_t)(lyr - 1) * 256;
#pragma unroll
        for (int j = 0; j < 8; ++j) x[j] = (x[j] - mean) * rstd * g[k0 + j] + bv[k0 + j];
      }
      f16x8 q8 = *(const f16x8*)(qkv16 + (size_t)i * 768 + k0);
      f16x8 k8 = *(const f16x8*)(qkv16 + (size_t)r * 768 + 256 + k0);
      float ps = 0.f;
#pragma unroll
      for (int j = 0; j < 8; ++j) {
        float f = SCALE_QK * (float)q8[j] * (float)k8[j] + x[j];
        v[j] = (half_t)f;
        ps += f;
        e32[r * 260 + k0 + j] = x[j];
      }
      psum[r * 32 + kb] = ps;
    }
    *(f16x8*)(ne5 + r * 512 + ((k0 * 2) ^ ((r & 7) << 4))) = v;
  }
  __syncthreads();
  if (tid < 192) {
    int hq = tid & 7;
    sc[tid] = psum[(tid >> 3) * 32 + hq * 4] + psum[(tid >> 3) * 32 + hq * 4 + 1] +
              psum[(tid >> 3) * 32 + hq * 4 + 2] + psum[(tid >> 3) * 32 + hq * 4 + 3];
  }
  __syncthreads();
  // ---- softmax over j per head (wave-parallel)
  if (tid < 256) {
    const int h = tid >> 5, j = tid & 31;
    float v = (j < 24) ? sc[j * 8 + h] : -1e30f;
    float mx = v;
#pragma unroll
    for (int off = 16; off; off >>= 1) mx = fmaxf(mx, __shfl_xor(mx, off));
    float ex = (j < 24) ? __expf(v - mx) : 0.f;
    float sum = ex;
#pragma unroll
    for (int off = 16; off; off >>= 1) sum += __shfl_xor(sum, off);
    if (j < 24) sc[j * 8 + h] = ex / sum;
  }
  __syncthreads();
  if (tid < 256) {
    const int d = tid, h = d >> 5;
    float a = 0.f;
#pragma unroll
    for (int j = 0; j < 24; ++j) a += sc[j * 8 + h] * (float)qkv16[(size_t)j * 768 + 512 + d];
    wvl[d] = a;
  }
  // ---- EO gemm
  {
    const float* eob = p.eo_b + (size_t)lyr * 256;
    gemm_rs<2, 8, 2, 256>(slot + OFF_EOT, 256, ne5,
      [&](int nt, int m, f32x4 v) {
        const int col = (nt * 8 + wv) * 16 + l15;
#pragma unroll
        for (int r4 = 0; r4 < 4; ++r4) {
          const int row = m * 16 + kg * 4 + r4;
          if (row < NNODE)
            aef[row * 257 + col] = fmaxf(v[r4] + eob[col], 0.f) + e32[row * 260 + col];
        }
      });
  }
  __syncthreads();
  // ---- LN1e -> eacc_out init (y + me_b2) + ae16g
  {
    const float* g = p.ln1e_g + (size_t)lyr * 256;
    const float* bv = p.ln1e_b + (size_t)lyr * 256;
    const float* mb2e = p.me_b2 + (size_t)lyr * 256;
    for (int r = wv; r < NNODE; r += 8) {
      float x[4];
#pragma unroll
      for (int j = 0; j < 4; ++j) x[j] = aef[r * 257 + lane * 4 + j];
      float s = x[0] + x[1] + x[2] + x[3];
      float s2 = x[0]*x[0] + x[1]*x[1] + x[2]*x[2] + x[3]*x[3];
#pragma unroll
      for (int off = 32; off; off >>= 1) { s += __shfl_xor(s, off); s2 += __shfl_xor(s2, off); }
      float mean = s * (1.f / 256.f);
      float rstd = rsqrtf(s2 * (1.f / 256.f) - mean * mean + 1e-5f);
      f16x4 hv; f32x4 ev;
#pragma unroll
      for (int j = 0; j < 4; ++j) {
        int c = lane * 4 + j;
        float y = (x[j] - mean) * rstd * g[c] + bv[c];
        ev[j] = y + mb2e[c];
        hv[j] = (half_t)y;
      }
      *(f32x4*)(eacc_out + (rowbase + r) * 256 + lane * 4) = ev;
      *(f16x4*)(ae16g + (rowbase + r) * 256 + lane * 4) = hv;
    }
  }
  // NO: an[c] = sum_k wvl[k] * NOT[c][k]
  {
    const half_t* NOT_ = slot + OFF_NOT;
    int c = tid & 255, hf = tid >> 8;
    float s = 0.f;
    const half_t* wp = NOT_ + (size_t)c * 256 + hf * 128;
#pragma unroll
    for (int k8 = 0; k8 < 16; ++k8) {
      f16x8 w8 = *(const f16x8*)(wp + k8 * 8);
#pragma unroll
      for (int j = 0; j < 8; ++j) s += wvl[hf * 128 + k8 * 8 + j] * (float)w8[j];
    }
    anr[hf * 256 + c] = s;
  }
  __syncthreads();
  // ---- LN1n (wave 0) -> an16g + nacc_out init
  if (wv == 0) {
    const float* nob = p.no_b + (size_t)lyr * 256;
    const float* g = p.ln1n_g + (size_t)lyr * 256;
    const float* bv = p.ln1n_b + (size_t)lyr * 256;
    const float* mb2 = p.mn_b2 + (size_t)lyr * 256;
    float x[4];
#pragma unroll
    for (int j = 0; j < 4; ++j) {
      int c = lane * 4 + j;
      x[j] = anr[c] + anr[256 + c] + nob[c] + ni[c];
    }
    float s = x[0] + x[1] + x[2] + x[3];
    float s2 = x[0]*x[0] + x[1]*x[1] + x[2]*x[2] + x[3]*x[3];
#pragma unroll
    for (int off = 32; off; off >>= 1) { s += __shfl_xor(s, off); s2 += __shfl_xor(s2, off); }
    float mean = s * (1.f / 256.f);
    float rstd = rsqrtf(s2 * (1.f / 256.f) - mean * mean + 1e-5f);
    f16x4 hv; f32x4 av;
#pragma unroll
    for (int j = 0; j < 4; ++j) {
      int c = lane * 4 + j;
      float y = (x[j] - mean) * rstd * g[c] + bv[c];
      hv[j] = (half_t)y;
      av[j] = y + mb2[c];
    }
    *(f16x4*)((half_t*)(ws + WS_AN16) + (size_t)(b * NNODE + i) * 256 + lane * 4) = hv;
    *(f32x4*)(nacc_out + (size_t)(b * NNODE + i) * 256 + lane * 4) = av;
  }
}

// ===== KB: edge ME1+ME2 -> eacc atomics (192 WGs) + node MN1+MN2 atomic (8 WGs) =====
__global__ __launch_bounds__(512, 2) void k_mlp(Params p, int lyr) {
  __shared__ __align__(16) char smem[73728];
  const int bid = blockIdx.x, tid = threadIdx.x;
  const int lane = tid & 63, wv = tid >> 6, l15 = lane & 15, kg = lane >> 4;
  float* ws = p.ws;
  half_t* wt = (half_t*)(ws + WS_WTF);
  const half_t* slot = wt + (size_t)(lyr % 3) * SLOT_F16;

  if (bid < 192) {
    const int rb = bid >> 3, hb = bid & 7;
    const int row0 = rb * 96;
    char* A16 = smem;            // [96][512B]
    char* hl = smem + 49152;     // [96][256B]
    f16x8 b1[8];
    load_b1<8>(slot + OFF_ME1T + (size_t)(hb * 128) * 256, 256, b1);
    const half_t* aeg = (const half_t*)(ws + WS_AE16) + (size_t)row0 * 256;
    for (int idx = tid; idx < 96 * 32; idx += 512) {
      int r = idx >> 5, c8 = idx & 31;
      f16x8 v = *(const f16x8*)(aeg + r * 256 + c8 * 8);
      *(f16x8*)(A16 + r * 512 + ((c8 * 16) ^ ((r & 7) << 4))) = v;
    }
    __syncthreads();
    const float* mb1 = p.me_b1 + (size_t)lyr * 1024 + hb * 128;
    gemm_rs_preb<8, 6, 256>(b1, A16,
      [&](int m, f32x4 v) {
        const int colb = wv * 16 + l15;
        const float bc = mb1[colb];
#pragma unroll
        for (int r4 = 0; r4 < 4; ++r4) {
          const int row = m * 16 + kg * 4 + r4;
          *(half_t*)(hl + row * 256 + ((colb * 2) ^ ((row & 7) << 4))) = (half_t)fmaxf(v[r4] + bc, 0.f);
        }
      });
    __syncthreads();
    float* ea = ws + WS_EACC + (lyr & 1) * EACC_STRIDE + (size_t)row0 * 256;
    gemm_rs<2, 4, 6, 128>(slot + OFF_ME2T + hb * 128, 1024, hl,
      [&](int nt, int m, f32x4 v) {
        const int col = (nt * 8 + wv) * 16 + l15;
#pragma unroll
        for (int r4 = 0; r4 < 4; ++r4)
          atomicAdd(&ea[(size_t)(m * 16 + kg * 4 + r4) * 256 + col], v[r4]);
      });
  } else {
    // node MN: hb = bid-192
    const int hb = bid - 192;
    char* A16 = smem;            // [96][512B]
    char* hl = smem + 49152;     // [96][256B]
    f16x8 b1[8];
    load_b1<8>(slot + OFF_MN1T + (size_t)(hb * 128) * 256, 256, b1);
    const half_t* ang = (const half_t*)(ws + WS_AN16);
    for (int idx = tid; idx < 96 * 32; idx += 512) {
      int r = idx >> 5, c8 = idx & 31;
      f16x8 v = *(const f16x8*)(ang + (size_t)r * 256 + c8 * 8);
      *(f16x8*)(A16 + r * 512 + ((c8 * 16) ^ ((r & 7) << 4))) = v;
    }
    __syncthreads();
    const float* mb1 = p.mn_b1 + (size_t)lyr * 1024 + hb * 128;
    gemm_rs_preb<8, 6, 256>(b1, A16,
      [&](int m, f32x4 v) {
        const int colb = wv * 16 + l15;
        const float bc = mb1[colb];
#pragma unroll
        for (int r4 = 0; r4 < 4; ++r4) {
          const int row = m * 16 + kg * 4 + r4;
          *(half_t*)(hl + row * 256 + ((colb * 2) ^ ((row & 7) << 4))) = (half_t)fmaxf(v[r4] + bc, 0.f);
        }
      });
    __syncthreads();
    float* nacc_out = ws + WS_NACC + (lyr & 1) * NACC_STRIDE;
    gemm_rs<2, 4, 6, 128>(slot + OFF_MN2T + hb * 128, 1024, hl,
      [&](int nt, int m, f32x4 v) {
        const int col = (nt * 8 + wv) * 16 + l15;
#pragma unroll
        for (int r4 = 0; r4 < 4; ++r4)
          atomicAdd(&nacc_out[(size_t)(m * 16 + kg * 4 + r4) * 256 + col], v[r4]);
      });
  }
}

// ================= output heads (inline final LNs, eacc-based) =====================
__global__ __launch_bounds__(512, 2) void k_out(Params p) {
  __shared__ __align__(16) char smem[49472];
  const int bid = blockIdx.x, tid = threadIdx.x;
  const int lane = tid & 63, wv = tid >> 6, l15 = lane & 15, kg = lane >> 4;
  float* ws = p.ws;
  half_t* wt = (half_t*)(ws + WS_WTF);
  const float* eacc = ws + WS_EACC + 1 * EACC_STRIDE;  // layer 63 parity
  if (bid < 96) {
    const int b = bid / NNODE, i = bid % NNODE;
    const size_t rowbase = (size_t)(b * NNODE + i) * NNODE;
    char* A16 = smem;
    float* h2f = (float*)(smem + 16384);
    const float* g = p.ln2e_g + (size_t)63 * 256;
    const float* bvv = p.ln2e_b + (size_t)63 * 256;
    for (int idx = tid; idx < 32 * 32; idx += 512) {
      int r = idx >> 5, kb = idx & 31, k0 = kb * 8;
      f16x8 v;
#pragma unroll
      for (int j = 0; j < 8; ++j) v[j] = (half_t)0.f;
      if (r < NNODE) {
        const size_t row = rowbase + r;
        float x[8];
        const f32x4 a = *(const f32x4*)(eacc + row * 256 + k0);
        const f32x4 b4 = *(const f32x4*)(eacc + row * 256 + k0 + 4);
#pragma unroll
        for (int j = 0; j < 4; ++j) { x[j] = a[j]; x[4 + j] = b4[j]; }
        float s = 0.f, s2 = 0.f;
#pragma unroll
        for (int j = 0; j < 8; ++j) { s += x[j]; s2 += x[j] * x[j]; }
#pragma unroll
        for (int off = 16; off; off >>= 1) { s += __shfl_xor(s, off); s2 += __shfl_xor(s2, off); }
        float mean = s * (1.f / 256.f);
        float rstd = rsqrtf(s2 * (1.f / 256.f) - mean * mean + 1e-5f);
#pragma unroll
        for (int j = 0; j < 8; ++j)
          v[j] = (half_t)((x[j] - mean) * rstd * g[k0 + j] + bvv[k0 + j]);
      }
      *(f16x8*)(A16 + r * 512 + ((k0 * 2) ^ ((r & 7) << 4))) = v;
    }
    __syncthreads();
    run_gemm_s<2, 8, 2, 256, 256>(wt + OFF_OUTE1T, A16,
      [&](int n, f32x4 (&accn)[2]) {
        const int col = (n * 8 + wv) * 16 + l15;
#pragma unroll
        for (int m = 0; m < 2; ++m)
#pragma unroll
          for (int r4 = 0; r4 < 4; ++r4) {
            const int row = m * 16 + kg * 4 + r4;
            h2f[row * 257 + col] = (row < NNODE) ? fmaxf(accn[m][r4] + p.outE_b1[col], 0.f) : 0.f;
          }
      });
    __syncthreads();
    for (int pr = tid; pr < 24 * 12; pr += 512) {
      int j = pr / 12, oc = pr % 12;
      float s = p.outE_b2[oc];
      for (int k = 0; k < 256; ++k) s += h2f[j * 257 + k] * p.outE_w2[k * 12 + oc];
      p.out[1248 + ((size_t)(b * NNODE + i) * NNODE + j) * 12 + oc] = s;
    }
  } else {
    const int nb = bid - 96, bq = nb >> 1, hf = nb & 1, i0 = hf * 12;
    float* nl = (float*)smem;               // [12][257]
    float* t1f = (float*)(smem + 12544);    // [12][257]
    const float* n_acc = ws + WS_NACC + 1 * NACC_STRIDE;   // layer 63 parity
    const float* g = p.ln2n_g + (size_t)63 * 256;
    const float* bvv = p.ln2n_b + (size_t)63 * 256;
    for (int r = wv; r < 12; r += 8) {
      const int row = bq * NNODE + i0 + r;
      const int c = lane * 4;
      f32x4 x = *(const f32x4*)(n_acc + (size_t)row * 256 + c);
      float s = x[0] + x[1] + x[2] + x[3];
      float s2 = x[0]*x[0] + x[1]*x[1] + x[2]*x[2] + x[3]*x[3];
#pragma unroll
      for (int off = 32; off; off >>= 1) { s += __shfl_xor(s, off); s2 += __shfl_xor(s2, off); }
      float mean = s * (1.f / 256.f);
      float rstd = rsqrtf(s2 * (1.f / 256.f) - mean * mean + 1e-5f);
      f32x4 y;
#pragma unroll
      for (int j = 0; j < 4; ++j) y[j] = (x[j] - mean) * rstd * g[c + j] + bvv[c + j];
      *(f32x4*)(nl + r * 257 + c) = y;
    }
    __syncthreads();
    {
      int col = tid & 255, rh = tid >> 8;
      float a6[6] = {0.f, 0.f, 0.f, 0.f, 0.f, 0.f};
      for (int k = 0; k < 256; ++k) {
        float w = p.outN_w1[(size_t)k * 256 + col];
#pragma unroll
        for (int r = 0; r < 6; ++r) a6[r] += nl[(rh * 6 + r) * 257 + k] * w;
      }
#pragma unroll
      for (int r = 0; r < 6; ++r)
        t1f[(rh * 6 + r) * 257 + col] = fmaxf(a6[r] + p.outN_b1[col], 0.f);
    }
    __syncthreads();
    for (int pr = tid; pr < 12 * 13; pr += 512) {
      int il = pr / 13, oc = pr % 13;
      float s = p.outN_b2[oc];
      for (int k = 0; k < 256; ++k) s += t1f[il * 257 + k] * p.outN_w2[k * 13 + oc];
      p.out[((size_t)(bq * NNODE) + i0 + il) * 13 + oc] = s;
    }
  }
}

extern "C" void kernel_launch(void* const* d_in, const int* in_sizes, int n_in,
                              void* d_out, int out_size, void* d_ws, size_t ws_size,
                              hipStream_t stream) {
  (void)in_sizes; (void)n_in; (void)out_size; (void)ws_size;
  Params p;
  const float* const* fi = (const float* const*)d_in;
  p.nodes = fi[0]; p.edges = fi[1]; p.conds = (const int*)d_in[2];
  p.inN_w1 = fi[3]; p.inN_b1 = fi[4]; p.inN_w2 = fi[5]; p.inN_b2 = fi[6];
  p.inE_w1 = fi[7]; p.inE_b1 = fi[8]; p.inE_w2 = fi[9]; p.inE_b2 = fi[10];
  p.inC_w1 = fi[11]; p.inC_b1 = fi[12]; p.inC_w2 = fi[13]; p.inC_b2 = fi[14];
  p.qkv_w = fi[15]; p.qkv_b = fi[16]; p.no_w = fi[17]; p.no_b = fi[18];
  p.eo_w = fi[19]; p.eo_b = fi[20];
  p.ln1n_g = fi[21]; p.ln1n_b = fi[22]; p.ln1e_g = fi[23]; p.ln1e_b = fi[24];
  p.mn_w1 = fi[25]; p.mn_b1 = fi[26]; p.mn_w2 = fi[27]; p.mn_b2 = fi[28];
  p.me_w1 = fi[29]; p.me_b1 = fi[30]; p.me_w2 = fi[31]; p.me_b2 = fi[32];
  p.ln2n_g = fi[33]; p.ln2n_b = fi[34]; p.ln2e_g = fi[35]; p.ln2e_b = fi[36];
  p.outN_w1 = fi[37]; p.outN_b1 = fi[38]; p.outN_w2 = fi[39]; p.outN_b2 = fi[40];
  p.outE_w1 = fi[41]; p.outE_b1 = fi[42]; p.outE_w2 = fi[43]; p.outE_b2 = fi[44];
  p.ws = (float*)d_ws; p.out = (float*)d_out;

  k_embedA<<<dim3(132), dim3(512), 0, stream>>>(p);
  k_embedB<<<dim3(104), dim3(512), 0, stream>>>(p);
  for (int l = 0; l < NLAYER; ++l) {
    k_attn<<<dim3(222), dim3(512), 0, stream>>>(p, l);
    k_mlp<<<dim3(200), dim3(512), 0, stream>>>(p, l);
  }
  k_out<<<dim3(104), dim3(512), 0, stream>>>(p);
}

// Round 14
// 2934.607 us; speedup vs baseline: 1.1691x; 1.1691x over previous
//
#include <hip/hip_runtime.h>

typedef _Float16 half_t;
typedef _Float16 f16x8 __attribute__((ext_vector_type(8)));
typedef _Float16 f16x4 __attribute__((ext_vector_type(4)));
typedef float f32x4 __attribute__((ext_vector_type(4)));

#define BB 4
#define NNODE 24
#define NLAYER 64
#define SCALE_QK 0.0625f

// ---- workspace layout (float offsets) ----
#define WS_C     0               // [4][256] f32
#define WS_N     1024            // [96][256] f32 (embed n(0))
#define WS_NACC  25600           // 2 x [96][256] f32 (parity = layer&1)
#define NACC_STRIDE 24576
#define WS_E     74752           // [2304][256] f32 (embed e(0))
#define WS_AE32  664576          // [2304][256] f32 (LN1e out = residual)
#define WS_AE16  1254400         // [2304][256] f16
#define WS_AN16  1549312         // [96][256] f16 (ends 1561600)
#define WS_EPART 1561600         // [8][2304][256] f16 ME2 partials
#define EPART_SLICE 589824       // halves per slice
#define WS_WTF   3920896         // f16 weight region
#define SLOT_F16 1376256
#define OFF_QKVT 0               // [768][256]
#define OFF_NOT  196608          // [256][256]
#define OFF_EOT  262144          // [256][256]
#define OFF_MN1T 327680          // [1024][256]
#define OFF_MN2T 589824          // [256][1024]
#define OFF_ME1T 851968          // [1024][256]
#define OFF_ME2T 1114112         // [256][1024]
#define OFF_INE2T  (3*SLOT_F16)          // [256][256]
#define OFF_OUTE1T (3*SLOT_F16 + 65536)  // [256][256]

struct Params {
  const float *nodes, *edges; const int* conds;
  const float *inN_w1,*inN_b1,*inN_w2,*inN_b2;
  const float *inE_w1,*inE_b1,*inE_w2,*inE_b2;
  const float *inC_w1,*inC_b1,*inC_w2,*inC_b2;
  const float *qkv_w,*qkv_b,*no_w,*no_b,*eo_w,*eo_b;
  const float *ln1n_g,*ln1n_b,*ln1e_g,*ln1e_b;
  const float *mn_w1,*mn_b1,*mn_w2,*mn_b2,*me_w1,*me_b1,*me_w2,*me_b2;
  const float *ln2n_g,*ln2n_b,*ln2e_g,*ln2e_b;
  const float *outN_w1,*outN_b1,*outN_w2,*outN_b2,*outE_w1,*outE_b1,*outE_w2,*outE_b2;
  float* ws; float* out;
};

// ---- register-stationary MFMA GEMM: B (f16 [N][K] global) preloaded into
// regs as one burst; A from XOR-swizzled LDS. 8 waves split N.
template<int NT, int KS, int MT, int LDAH>
__device__ __forceinline__ void gemm_rs_acc(const half_t* __restrict__ WT, int ldb,
                                            const char* __restrict__ A,
                                            f32x4 (&acc)[NT][MT]) {
  const int lane = threadIdx.x & 63;
  const int wv = threadIdx.x >> 6;
  const int l15 = lane & 15;
  const int kg = lane >> 4;
  f16x8 b[NT][KS];
#pragma unroll
  for (int nt = 0; nt < NT; ++nt) {
    const int col = (nt * 8 + wv) * 16 + l15;
#pragma unroll
    for (int ks = 0; ks < KS; ++ks)
      b[nt][ks] = *(const f16x8*)(WT + (size_t)col * ldb + ks * 32 + kg * 8);
  }
#pragma unroll
  for (int m = 0; m < MT; ++m) {
    f16x8 a[KS];
    const int row = m * 16 + l15;
#pragma unroll
    for (int ks = 0; ks < KS; ++ks)
      a[ks] = *(const f16x8*)(A + row * (LDAH * 2) + (((ks * 32 + kg * 8) * 2) ^ ((row & 7) << 4)));
#pragma unroll
    for (int ks = 0; ks < KS; ++ks)
#pragma unroll
      for (int nt = 0; nt < NT; ++nt)
        acc[nt][m] = __builtin_amdgcn_mfma_f32_16x16x32_f16(a[ks], b[nt][ks], acc[nt][m], 0, 0, 0);
  }
}

template<int NT, int KS, int MT, int LDAH, typename EPI>
__device__ __forceinline__ void gemm_rs(const half_t* __restrict__ WT, int ldb,
                                        const char* __restrict__ A, EPI epi) {
  f32x4 acc[NT][MT];
#pragma unroll
  for (int nt = 0; nt < NT; ++nt)
#pragma unroll
    for (int m = 0; m < MT; ++m) {
      f32x4 z = {0.f, 0.f, 0.f, 0.f};
      acc[nt][m] = z;
    }
  gemm_rs_acc<NT, KS, MT, LDAH>(WT, ldb, A, acc);
#pragma unroll
  for (int nt = 0; nt < NT; ++nt)
#pragma unroll
    for (int m = 0; m < MT; ++m)
      epi(nt, m, acc[nt][m]);
}

// ---- legacy batched gemm (embed/out kernels) ----
template<int NTW, int KT, int MT, int LDA, int LDB, typename EPI>
__device__ __forceinline__ void run_gemm_s(const half_t* __restrict__ WT,
                                           const char* __restrict__ A,
                                           EPI epi) {
  const int lane = threadIdx.x & 63;
  const int wv = threadIdx.x >> 6;
  const int l15 = lane & 15;
  const int kg = lane >> 4;
  constexpr int NC = KT / 8;
  constexpr int TC = NC * NTW;
  f16x8 bb[2][8];
  auto ldb = [&](int c, int w) {
    const int kc = c / NTW, n = c % NTW;
    const half_t* bp = WT + (size_t)((n * 8 + wv) * 16 + l15) * LDB + kc * 256 + kg * 8;
#pragma unroll
    for (int q = 0; q < 8; ++q) bb[w][q] = *(const f16x8*)(bp + q * 32);
  };
  f32x4 acc[NTW][MT];
#pragma unroll
  for (int n = 0; n < NTW; ++n)
#pragma unroll
    for (int m = 0; m < MT; ++m) {
      f32x4 z = {0.f, 0.f, 0.f, 0.f};
      acc[n][m] = z;
    }
  ldb(0, 0);
#pragma unroll
  for (int kc = 0; kc < NC; ++kc) {
    f16x8 a[8][MT];
#pragma unroll
    for (int q = 0; q < 8; ++q) {
      const int k0 = (kc * 8 + q) * 32 + kg * 8;
#pragma unroll
      for (int m = 0; m < MT; ++m) {
        const int row = m * 16 + l15;
        a[q][m] = *(const f16x8*)(A + row * (LDA * 2) + ((k0 * 2) ^ ((row & 7) << 4)));
      }
    }
#pragma unroll
    for (int n = 0; n < NTW; ++n) {
      const int c = kc * NTW + n;
      if (c + 1 < TC) ldb(c + 1, (c + 1) & 1);
#pragma unroll
      for (int q = 0; q < 8; ++q)
#pragma unroll
        for (int m = 0; m < MT; ++m)
          acc[n][m] = __builtin_amdgcn_mfma_f32_16x16x32_f16(a[q][m], bb[c & 1][q], acc[n][m], 0, 0, 0);
    }
  }
#pragma unroll
  for (int n = 0; n < NTW; ++n) epi(n, acc[n]);
}

// ---- 64x64 transpose+convert fp32 -> f16 tile ----
__device__ void conv_matrix_tile(const float* __restrict__ src, half_t* __restrict__ dst,
                                 int K, int Nn, int tk, int tn, char* smem) {
  float* tl = (float*)smem;  // [64][65]
  const int t = threadIdx.x;
  const int c = t & 63;
  const int r0 = t >> 6;
  for (int r = r0; r < 64; r += 8)
    tl[r * 65 + c] = src[(size_t)(tk * 64 + r) * Nn + tn * 64 + c];
  __syncthreads();
  for (int r = r0; r < 64; r += 8)
    dst[(size_t)(tn * 64 + r) * K + tk * 64 + c] = (half_t)tl[c * 65 + r];
  __syncthreads();
}

__device__ void conv_layer_tile(const Params& p, half_t* slot, int lw, int tile, char* smem) {
  if (tile < 48)       { conv_matrix_tile(p.qkv_w + (size_t)lw*196608, slot+OFF_QKVT, 256, 768, tile & 3, tile >> 2, smem); }
  else if (tile < 64)  { int t2 = tile-48;  conv_matrix_tile(p.no_w  + (size_t)lw*65536,  slot+OFF_NOT,  256, 256, t2 & 3,  t2 >> 2, smem); }
  else if (tile < 80)  { int t2 = tile-64;  conv_matrix_tile(p.eo_w  + (size_t)lw*65536,  slot+OFF_EOT,  256, 256, t2 & 3,  t2 >> 2, smem); }
  else if (tile < 144) { int t2 = tile-80;  conv_matrix_tile(p.mn_w1 + (size_t)lw*262144, slot+OFF_MN1T, 256, 1024, t2 & 3, t2 >> 2, smem); }
  else if (tile < 208) { int t2 = tile-144; conv_matrix_tile(p.mn_w2 + (size_t)lw*262144, slot+OFF_MN2T, 1024, 256, t2 & 15, t2 >> 4, smem); }
  else if (tile < 272) { int t2 = tile-208; conv_matrix_tile(p.me_w1 + (size_t)lw*262144, slot+OFF_ME1T, 256, 1024, t2 & 3, t2 >> 2, smem); }
  else                 { int t2 = tile-272; conv_matrix_tile(p.me_w2 + (size_t)lw*262144, slot+OFF_ME2T, 1024, 256, t2 & 15, t2 >> 4, smem); }
}

// ================= embed A =================
__global__ __launch_bounds__(512, 2) void k_embedA(Params p) {
  __shared__ __align__(16) char smem[17024];
  const int bid = blockIdx.x, tid = threadIdx.x;
  float* ws = p.ws;
  half_t* wt = (half_t*)(ws + WS_WTF);
  if (bid < 4) {
    const int b = bid;
    const int cond = p.conds[b];
    float* t1 = (float*)smem;
    if (tid < 256) t1[tid] = fmaxf(p.inC_w1[(size_t)cond * 256 + tid] + p.inC_b1[tid], 0.f);
    __syncthreads();
    if (tid < 256) {
      float s = p.inC_b2[tid];
      for (int k = 0; k < 256; ++k) s += t1[k] * p.inC_w2[(size_t)k * 256 + tid];
      ws[WS_C + b * 256 + tid] = fmaxf(s, 0.f);
    }
  } else {
    for (int job = bid - 4; job < 704; job += 128) {
      if (job < 336)      conv_layer_tile(p, wt, 0, job, smem);
      else if (job < 672) conv_layer_tile(p, wt + SLOT_F16, 1, job - 336, smem);
      else if (job < 688) { int t2 = job - 672; conv_matrix_tile(p.inE_w2,  wt + OFF_INE2T,  256, 256, t2 & 3, t2 >> 2, smem); }
      else                { int t2 = job - 688; conv_matrix_tile(p.outE_w1, wt + OFF_OUTE1T, 256, 256, t2 & 3, t2 >> 2, smem); }
    }
  }
}

// ================= embed B: edge embed (MFMA), node embed =================
__global__ __launch_bounds__(512, 2) void k_embedB(Params p) {
  __shared__ __align__(16) char smem[24640];
  const int bid = blockIdx.x, tid = threadIdx.x;
  const int lane = tid & 63, wv = tid >> 6, l15 = lane & 15, kg = lane >> 4;
  float* ws = p.ws;
  half_t* wt = (half_t*)(ws + WS_WTF);
  float* e0 = ws + WS_E;
  float* n0 = ws + WS_N;
  if (bid < 96) {
    const int b = bid / NNODE, i = bid % NNODE;
    float* eb = (float*)smem;        // [24][12]
    char* t16 = smem + 2048;         // [32][512] f16
    for (int idx = tid; idx < 24 * 12; idx += 512)
      eb[idx] = p.edges[((size_t)(b * NNODE + i) * NNODE + idx / 12) * 12 + idx % 12];
    __syncthreads();
    for (int idx = tid; idx < 32 * 32; idx += 512) {
      int r = idx >> 5, kb = idx & 31, k0 = kb * 8;
      f16x8 v;
#pragma unroll
      for (int j = 0; j < 8; ++j) v[j] = (half_t)0.f;
      if (r < NNODE) {
#pragma unroll
        for (int j = 0; j < 8; ++j) {
          int col = k0 + j;
          float s = p.inE_b1[col];
          for (int kk = 0; kk < 12; ++kk) s += eb[r * 12 + kk] * p.inE_w1[kk * 256 + col];
          v[j] = (half_t)fmaxf(s, 0.f);
        }
      }
      *(f16x8*)(t16 + r * 512 + ((k0 * 2) ^ ((r & 7) << 4))) = v;
    }
    __syncthreads();
    run_gemm_s<2, 8, 2, 256, 256>(wt + OFF_INE2T, t16,
      [&](int n, f32x4 (&accn)[2]) {
        const int col = (n * 8 + wv) * 16 + l15;
        const float bcol = p.inE_b2[col];
#pragma unroll
        for (int m = 0; m < 2; ++m)
#pragma unroll
          for (int r4 = 0; r4 < 4; ++r4) {
            const int row = m * 16 + kg * 4 + r4;
            if (row < NNODE)
              e0[((size_t)(b * NNODE + i) * NNODE + row) * 256 + col] = fmaxf(accn[m][r4] + bcol, 0.f);
          }
      });
  } else {
    const int nb = bid - 96, b = nb >> 1, hf = nb & 1, i0 = hf * 12;
    float* nd = (float*)smem;            // [12][16]
    float* t1 = (float*)(smem + 1024);   // [12][257]
    for (int idx = tid; idx < 12 * 13; idx += 512)
      nd[(idx / 13) * 16 + (idx % 13)] = p.nodes[(size_t)(b * NNODE + i0 + idx / 13) * 13 + idx % 13];
    __syncthreads();
    for (int idx = tid; idx < 12 * 256; idx += 512) {
      int r = idx >> 8, col = idx & 255;
      float s = p.inN_b1[col];
      for (int kk = 0; kk < 13; ++kk) s += nd[r * 16 + kk] * p.inN_w1[kk * 256 + col];
      t1[r * 257 + col] = fmaxf(s, 0.f);
    }
    __syncthreads();
    {
      int col = tid & 255, rh = tid >> 8;
      float a6[6] = {0.f, 0.f, 0.f, 0.f, 0.f, 0.f};
      for (int k = 0; k < 256; ++k) {
        float w = p.inN_w2[(size_t)k * 256 + col];
#pragma unroll
        for (int r = 0; r < 6; ++r) a6[r] += t1[(rh * 6 + r) * 257 + k] * w;
      }
#pragma unroll
      for (int r = 0; r < 6; ++r) {
        int row = rh * 6 + r;
        n0[(size_t)(b * NNODE + i0 + row) * 256 + col] = fmaxf(a6[r] + p.inN_b2[col], 0.f);
      }
    }
  }
}

// ===== KA: LN2n-recon + QKV + LN2e-recon + attn + EO + LN1e + NO + LN1n =====
__global__ __launch_bounds__(512, 2) void k_attn(Params p, int lyr) {
  __shared__ __align__(16) char smem[139488];
  const int bid = blockIdx.x, tid = threadIdx.x;
  const int lane = tid & 63, wv = tid >> 6, l15 = lane & 15, kg = lane >> 4;
  float* ws = p.ws;
  half_t* wt = (half_t*)(ws + WS_WTF);
  const half_t* slot = wt + (size_t)(lyr % 3) * SLOT_F16;

  if (bid >= 96) {
    if (lyr + 2 < NLAYER) {
      half_t* dslot = wt + (size_t)((lyr + 2) % 3) * SLOT_F16;
      for (int tile = bid - 96; tile < 336; tile += 126)
        conv_layer_tile(p, dslot, lyr + 2, tile, smem);
    }
    return;
  }
  const int b = bid / NNODE, i = bid % NNODE;
  const size_t rowbase = (size_t)(b * NNODE + i) * NNODE;
  char* nc16 = smem;                        // [32][512]
  half_t* qkv16 = (half_t*)(smem + 16384);  // [32][768]
  char* ne5 = smem + 65536;                 // [32][512]
  float* e32 = (float*)(smem + 81920);      // [24][260]
  float* psum = (float*)(smem + 106880);    // [24][32]
  float* sc = (float*)(smem + 109952);      // [24][8]
  float* wvl = (float*)(smem + 110720);     // [256]
  float* ni = (float*)(smem + 111744);      // [256]
  float* anr = (float*)(smem + 112768);     // [2][256]
  float* aef = (float*)(smem + 114816);     // [24][257]
  float* ae32 = ws + WS_AE32;
  half_t* ae16g = (half_t*)(ws + WS_AE16);
  const half_t* epart = (const half_t*)(ws + WS_EPART);
  const float* nacc_in = ws + WS_NACC + ((lyr + 1) & 1) * NACC_STRIDE;
  float* nacc_out = ws + WS_NACC + (lyr & 1) * NACC_STRIDE;
  const float* cb = ws + WS_C + b * 256;

  // ---- phase 1: n(l) rows of batch b (LN2n recon for l>=1) -> nc16 (+c), ni
  for (int r = wv; r < 32; r += 8) {
    const int c = lane * 4;
    f16x4 hv;
    if (r < NNODE) {
      f32x4 y;
      if (lyr == 0) {
        y = *(const f32x4*)(ws + WS_N + (size_t)(b * NNODE + r) * 256 + c);
      } else {
        f32x4 x = *(const f32x4*)(nacc_in + (size_t)(b * NNODE + r) * 256 + c);
        float s = x[0] + x[1] + x[2] + x[3];
        float s2 = x[0]*x[0] + x[1]*x[1] + x[2]*x[2] + x[3]*x[3];
#pragma unroll
        for (int off = 32; off; off >>= 1) { s += __shfl_xor(s, off); s2 += __shfl_xor(s2, off); }
        float mean = s * (1.f / 256.f);
        float rstd = rsqrtf(s2 * (1.f / 256.f) - mean * mean + 1e-5f);
        const float* g = p.ln2n_g + (size_t)(lyr - 1) * 256;
        const float* bv = p.ln2n_b + (size_t)(lyr - 1) * 256;
#pragma unroll
        for (int j = 0; j < 4; ++j) y[j] = (x[j] - mean) * rstd * g[c + j] + bv[c + j];
      }
      if (r == i) *(f32x4*)(ni + c) = y;
#pragma unroll
      for (int j = 0; j < 4; ++j) hv[j] = (half_t)(y[j] + cb[c + j]);
    } else {
#pragma unroll
      for (int j = 0; j < 4; ++j) hv[j] = (half_t)0.f;
    }
    *(f16x4*)(nc16 + r * 512 + ((lane * 8) ^ ((r & 7) << 4))) = hv;
  }
  __syncthreads();
  // ---- phase 2: QKV gemm (24 rows x 768) -> qkv16 (f16)
  {
    const float* qb = p.qkv_b + (size_t)lyr * 768;
#pragma unroll
    for (int nn = 0; nn < 3; ++nn) {
      gemm_rs<2, 8, 2, 256>(slot + OFF_QKVT + (size_t)(nn * 256) * 256, 256, nc16,
        [&](int nt, int m, f32x4 v) {
          const int gcol = nn * 256 + (nt * 8 + wv) * 16 + l15;
          const float bc = qb[gcol];
#pragma unroll
          for (int r4 = 0; r4 < 4; ++r4) {
            const int row = m * 16 + kg * 4 + r4;
            qkv16[(size_t)row * 768 + gcol] = (half_t)(v[r4] + bc);
          }
        });
    }
  }
  __syncthreads();
  // ---- phase 3: LN2e recon + scores + ne5 + e32
  for (int idx = tid; idx < 32 * 32; idx += 512) {
    int r = idx >> 5, kb = idx & 31, k0 = kb * 8;
    f16x8 v;
#pragma unroll
    for (int j = 0; j < 8; ++j) v[j] = (half_t)0.f;
    if (r < NNODE) {
      const size_t row = rowbase + r;
      float x[8];
      if (lyr == 0) {
        const f32x4 a = *(const f32x4*)(ws + WS_E + row * 256 + k0);
        const f32x4 b4 = *(const f32x4*)(ws + WS_E + row * 256 + k0 + 4);
#pragma unroll
        for (int j = 0; j < 4; ++j) { x[j] = a[j]; x[4 + j] = b4[j]; }
      } else {
        const float* mb2 = p.me_b2 + (size_t)(lyr - 1) * 256;
        const f32x4 a = *(const f32x4*)(ae32 + row * 256 + k0);
        const f32x4 b4 = *(const f32x4*)(ae32 + row * 256 + k0 + 4);
#pragma unroll
        for (int j = 0; j < 4; ++j) { x[j] = a[j] + mb2[k0 + j]; x[4 + j] = b4[j] + mb2[k0 + 4 + j]; }
#pragma unroll
        for (int hb = 0; hb < 8; ++hb) {
          f16x8 pv = *(const f16x8*)(epart + (size_t)hb * EPART_SLICE + row * 256 + k0);
#pragma unroll
          for (int j = 0; j < 8; ++j) x[j] += (float)pv[j];
        }
        float s = 0.f, s2 = 0.f;
#pragma unroll
        for (int j = 0; j < 8; ++j) { s += x[j]; s2 += x[j] * x[j]; }
#pragma unroll
        for (int off = 16; off; off >>= 1) { s += __shfl_xor(s, off); s2 += __shfl_xor(s2, off); }
        float mean = s * (1.f / 256.f);
        float rstd = rsqrtf(s2 * (1.f / 256.f) - mean * mean + 1e-5f);
        const float* g = p.ln2e_g + (size_t)(lyr - 1) * 256;
        const float* bv = p.ln2e_b + (size_t)(lyr - 1) * 256;
#pragma unroll
        for (int j = 0; j < 8; ++j) x[j] = (x[j] - mean) * rstd * g[k0 + j] + bv[k0 + j];
      }
      f16x8 q8 = *(const f16x8*)(qkv16 + (size_t)i * 768 + k0);
      f16x8 k8 = *(const f16x8*)(qkv16 + (size_t)r * 768 + 256 + k0);
      float ps = 0.f;
#pragma unroll
      for (int j = 0; j < 8; ++j) {
        float f = SCALE_QK * (float)q8[j] * (float)k8[j] + x[j];
        v[j] = (half_t)f;
        ps += f;
        e32[r * 260 + k0 + j] = x[j];
      }
      psum[r * 32 + kb] = ps;
    }
    *(f16x8*)(ne5 + r * 512 + ((k0 * 2) ^ ((r & 7) << 4))) = v;
  }
  __syncthreads();
  if (tid < 192) {
    int hq = tid & 7;
    sc[tid] = psum[(tid >> 3) * 32 + hq * 4] + psum[(tid >> 3) * 32 + hq * 4 + 1] +
              psum[(tid >> 3) * 32 + hq * 4 + 2] + psum[(tid >> 3) * 32 + hq * 4 + 3];
  }
  __syncthreads();
  if (tid < 8) {
    const int h = tid;
    float mx = -1e30f;
#pragma unroll
    for (int j = 0; j < 24; ++j) mx = fmaxf(mx, sc[j * 8 + h]);
    float ex[24]; float ssum = 0.f;
#pragma unroll
    for (int j = 0; j < 24; ++j) { ex[j] = __expf(sc[j * 8 + h] - mx); ssum += ex[j]; }
    float inv = 1.f / ssum;
#pragma unroll
    for (int j = 0; j < 24; ++j) sc[j * 8 + h] = ex[j] * inv;
  }
  __syncthreads();
  if (tid < 256) {
    const int d = tid, h = d >> 5;
    float a = 0.f;
#pragma unroll
    for (int j = 0; j < 24; ++j) a += sc[j * 8 + h] * (float)qkv16[(size_t)j * 768 + 512 + d];
    wvl[d] = a;
  }
  // ---- EO gemm
  {
    const float* eob = p.eo_b + (size_t)lyr * 256;
    gemm_rs<2, 8, 2, 256>(slot + OFF_EOT, 256, ne5,
      [&](int nt, int m, f32x4 v) {
        const int col = (nt * 8 + wv) * 16 + l15;
#pragma unroll
        for (int r4 = 0; r4 < 4; ++r4) {
          const int row = m * 16 + kg * 4 + r4;
          if (row < NNODE)
            aef[row * 257 + col] = fmaxf(v[r4] + eob[col], 0.f) + e32[row * 260 + col];
        }
      });
  }
  __syncthreads();
  // ---- LN1e -> ae32 + ae16g ; NO partial sums in parallel
  {
    const float* g = p.ln1e_g + (size_t)lyr * 256;
    const float* bv = p.ln1e_b + (size_t)lyr * 256;
    for (int r = wv; r < NNODE; r += 8) {
      float x[4];
#pragma unroll
      for (int j = 0; j < 4; ++j) x[j] = aef[r * 257 + lane * 4 + j];
      float s = x[0] + x[1] + x[2] + x[3];
      float s2 = x[0]*x[0] + x[1]*x[1] + x[2]*x[2] + x[3]*x[3];
#pragma unroll
      for (int off = 32; off; off >>= 1) { s += __shfl_xor(s, off); s2 += __shfl_xor(s2, off); }
      float mean = s * (1.f / 256.f);
      float rstd = rsqrtf(s2 * (1.f / 256.f) - mean * mean + 1e-5f);
      f16x4 hv; f32x4 yv;
#pragma unroll
      for (int j = 0; j < 4; ++j) {
        int c = lane * 4 + j;
        float y = (x[j] - mean) * rstd * g[c] + bv[c];
        yv[j] = y; hv[j] = (half_t)y;
      }
      *(f32x4*)(ae32 + (rowbase + r) * 256 + lane * 4) = yv;
      *(f16x4*)(ae16g + (rowbase + r) * 256 + lane * 4) = hv;
    }
  }
  // NO: an[c] = sum_k wvl[k] * NOT[c][k]
  {
    const half_t* NOT_ = slot + OFF_NOT;
    int c = tid & 255, hf = tid >> 8;
    float s = 0.f;
    const half_t* wp = NOT_ + (size_t)c * 256 + hf * 128;
#pragma unroll
    for (int k8 = 0; k8 < 16; ++k8) {
      f16x8 w8 = *(const f16x8*)(wp + k8 * 8);
#pragma unroll
      for (int j = 0; j < 8; ++j) s += wvl[hf * 128 + k8 * 8 + j] * (float)w8[j];
    }
    anr[hf * 256 + c] = s;
  }
  __syncthreads();
  // ---- LN1n (wave 0) -> an16g + nacc_out init
  if (wv == 0) {
    const float* nob = p.no_b + (size_t)lyr * 256;
    const float* g = p.ln1n_g + (size_t)lyr * 256;
    const float* bv = p.ln1n_b + (size_t)lyr * 256;
    const float* mb2 = p.mn_b2 + (size_t)lyr * 256;
    float x[4];
#pragma unroll
    for (int j = 0; j < 4; ++j) {
      int c = lane * 4 + j;
      x[j] = anr[c] + anr[256 + c] + nob[c] + ni[c];
    }
    float s = x[0] + x[1] + x[2] + x[3];
    float s2 = x[0]*x[0] + x[1]*x[1] + x[2]*x[2] + x[3]*x[3];
#pragma unroll
    for (int off = 32; off; off >>= 1) { s += __shfl_xor(s, off); s2 += __shfl_xor(s2, off); }
    float mean = s * (1.f / 256.f);
    float rstd = rsqrtf(s2 * (1.f / 256.f) - mean * mean + 1e-5f);
    f16x4 hv; f32x4 av;
#pragma unroll
    for (int j = 0; j < 4; ++j) {
      int c = lane * 4 + j;
      float y = (x[j] - mean) * rstd * g[c] + bv[c];
      hv[j] = (half_t)y;
      av[j] = y + mb2[c];
    }
    *(f16x4*)((half_t*)(ws + WS_AN16) + (size_t)(b * NNODE + i) * 256 + lane * 4) = hv;
    *(f32x4*)(nacc_out + (size_t)(b * NNODE + i) * 256 + lane * 4) = av;
  }
}

// ===== KB: edge ME1+ME2 partials (192 WGs) + node MN1+MN2 atomic (8 WGs) =====
__global__ __launch_bounds__(512, 2) void k_mlp(Params p, int lyr) {
  __shared__ __align__(16) char smem[73728];
  const int bid = blockIdx.x, tid = threadIdx.x;
  const int lane = tid & 63, wv = tid >> 6, l15 = lane & 15, kg = lane >> 4;
  float* ws = p.ws;
  half_t* wt = (half_t*)(ws + WS_WTF);
  const half_t* slot = wt + (size_t)(lyr % 3) * SLOT_F16;

  if (bid < 192) {
    const int rb = bid >> 3, hb = bid & 7;
    const int row0 = rb * 96;
    char* A16 = smem;            // [96][512B]
    char* hl = smem + 49152;     // [96][256B]
    const half_t* aeg = (const half_t*)(ws + WS_AE16) + (size_t)row0 * 256;
    for (int idx = tid; idx < 96 * 32; idx += 512) {
      int r = idx >> 5, c8 = idx & 31;
      f16x8 v = *(const f16x8*)(aeg + r * 256 + c8 * 8);
      *(f16x8*)(A16 + r * 512 + ((c8 * 16) ^ ((r & 7) << 4))) = v;
    }
    __syncthreads();
    const float* mb1 = p.me_b1 + (size_t)lyr * 1024 + hb * 128;
    gemm_rs<1, 8, 6, 256>(slot + OFF_ME1T + (size_t)(hb * 128) * 256, 256, A16,
      [&](int nt, int m, f32x4 v) {
        const int colb = wv * 16 + l15;
        const float bc = mb1[colb];
#pragma unroll
        for (int r4 = 0; r4 < 4; ++r4) {
          const int row = m * 16 + kg * 4 + r4;
          *(half_t*)(hl + row * 256 + ((colb * 2) ^ ((row & 7) << 4))) = (half_t)fmaxf(v[r4] + bc, 0.f);
        }
      });
    __syncthreads();
    half_t* ep = (half_t*)(ws + WS_EPART) + (size_t)hb * EPART_SLICE + (size_t)row0 * 256;
    gemm_rs<2, 4, 6, 128>(slot + OFF_ME2T + hb * 128, 1024, hl,
      [&](int nt, int m, f32x4 v) {
        const int col = (nt * 8 + wv) * 16 + l15;
#pragma unroll
        for (int r4 = 0; r4 < 4; ++r4)
          ep[(size_t)(m * 16 + kg * 4 + r4) * 256 + col] = (half_t)v[r4];
      });
  } else {
    // node MN: hb = bid-192
    const int hb = bid - 192;
    char* A16 = smem;            // [96][512B]
    char* hl = smem + 49152;     // [96][256B]
    const half_t* ang = (const half_t*)(ws + WS_AN16);
    for (int idx = tid; idx < 96 * 32; idx += 512) {
      int r = idx >> 5, c8 = idx & 31;
      f16x8 v = *(const f16x8*)(ang + (size_t)r * 256 + c8 * 8);
      *(f16x8*)(A16 + r * 512 + ((c8 * 16) ^ ((r & 7) << 4))) = v;
    }
    __syncthreads();
    const float* mb1 = p.mn_b1 + (size_t)lyr * 1024 + hb * 128;
    gemm_rs<1, 8, 6, 256>(slot + OFF_MN1T + (size_t)(hb * 128) * 256, 256, A16,
      [&](int nt, int m, f32x4 v) {
        const int colb = wv * 16 + l15;
        const float bc = mb1[colb];
#pragma unroll
        for (int r4 = 0; r4 < 4; ++r4) {
          const int row = m * 16 + kg * 4 + r4;
          *(half_t*)(hl + row * 256 + ((colb * 2) ^ ((row & 7) << 4))) = (half_t)fmaxf(v[r4] + bc, 0.f);
        }
      });
    __syncthreads();
    float* nacc_out = ws + WS_NACC + (lyr & 1) * NACC_STRIDE;
    gemm_rs<2, 4, 6, 128>(slot + OFF_MN2T + hb * 128, 1024, hl,
      [&](int nt, int m, f32x4 v) {
        const int col = (nt * 8 + wv) * 16 + l15;
#pragma unroll
        for (int r4 = 0; r4 < 4; ++r4)
          atomicAdd(&nacc_out[(size_t)(m * 16 + kg * 4 + r4) * 256 + col], v[r4]);
      });
  }
}

// ================= output heads (inline final LNs) =====================
__global__ __launch_bounds__(512, 2) void k_out(Params p) {
  __shared__ __align__(16) char smem[49472];
  const int bid = blockIdx.x, tid = threadIdx.x;
  const int lane = tid & 63, wv = tid >> 6, l15 = lane & 15, kg = lane >> 4;
  float* ws = p.ws;
  half_t* wt = (half_t*)(ws + WS_WTF);
  const float* ae32 = ws + WS_AE32;
  const half_t* epart = (const half_t*)(ws + WS_EPART);
  if (bid < 96) {
    const int b = bid / NNODE, i = bid % NNODE;
    const size_t rowbase = (size_t)(b * NNODE + i) * NNODE;
    char* A16 = smem;
    float* h2f = (float*)(smem + 16384);
    const float* mb2 = p.me_b2 + (size_t)63 * 256;
    const float* g = p.ln2e_g + (size_t)63 * 256;
    const float* bvv = p.ln2e_b + (size_t)63 * 256;
    for (int idx = tid; idx < 32 * 32; idx += 512) {
      int r = idx >> 5, kb = idx & 31, k0 = kb * 8;
      f16x8 v;
#pragma unroll
      for (int j = 0; j < 8; ++j) v[j] = (half_t)0.f;
      if (r < NNODE) {
        const size_t row = rowbase + r;
        float x[8];
        const f32x4 a = *(const f32x4*)(ae32 + row * 256 + k0);
        const f32x4 b4 = *(const f32x4*)(ae32 + row * 256 + k0 + 4);
#pragma unroll
        for (int j = 0; j < 4; ++j) { x[j] = a[j] + mb2[k0 + j]; x[4 + j] = b4[j] + mb2[k0 + 4 + j]; }
#pragma unroll
        for (int hb = 0; hb < 8; ++hb) {
          f16x8 pv = *(const f16x8*)(epart + (size_t)hb * EPART_SLICE + row * 256 + k0);
#pragma unroll
          for (int j = 0; j < 8; ++j) x[j] += (float)pv[j];
        }
        float s = 0.f, s2 = 0.f;
#pragma unroll
        for (int j = 0; j < 8; ++j) { s += x[j]; s2 += x[j] * x[j]; }
#pragma unroll
        for (int off = 16; off; off >>= 1) { s += __shfl_xor(s, off); s2 += __shfl_xor(s2, off); }
        float mean = s * (1.f / 256.f);
        float rstd = rsqrtf(s2 * (1.f / 256.f) - mean * mean + 1e-5f);
#pragma unroll
        for (int j = 0; j < 8; ++j)
          v[j] = (half_t)((x[j] - mean) * rstd * g[k0 + j] + bvv[k0 + j]);
      }
      *(f16x8*)(A16 + r * 512 + ((k0 * 2) ^ ((r & 7) << 4))) = v;
    }
    __syncthreads();
    run_gemm_s<2, 8, 2, 256, 256>(wt + OFF_OUTE1T, A16,
      [&](int n, f32x4 (&accn)[2]) {
        const int col = (n * 8 + wv) * 16 + l15;
#pragma unroll
        for (int m = 0; m < 2; ++m)
#pragma unroll
          for (int r4 = 0; r4 < 4; ++r4) {
            const int row = m * 16 + kg * 4 + r4;
            h2f[row * 257 + col] = (row < NNODE) ? fmaxf(accn[m][r4] + p.outE_b1[col], 0.f) : 0.f;
          }
      });
    __syncthreads();
    for (int pr = tid; pr < 24 * 12; pr += 512) {
      int j = pr / 12, oc = pr % 12;
      float s = p.outE_b2[oc];
      for (int k = 0; k < 256; ++k) s += h2f[j * 257 + k] * p.outE_w2[k * 12 + oc];
      p.out[1248 + ((size_t)(b * NNODE + i) * NNODE + j) * 12 + oc] = s;
    }
  } else {
    const int nb = bid - 96, bq = nb >> 1, hf = nb & 1, i0 = hf * 12;
    float* nl = (float*)smem;               // [12][257]
    float* t1f = (float*)(smem + 12544);    // [12][257]
    const float* n_acc = ws + WS_NACC + 1 * NACC_STRIDE;   // layer 63 parity
    const float* g = p.ln2n_g + (size_t)63 * 256;
    const float* bvv = p.ln2n_b + (size_t)63 * 256;
    for (int r = wv; r < 12; r += 8) {
      const int row = bq * NNODE + i0 + r;
      const int c = lane * 4;
      f32x4 x = *(const f32x4*)(n_acc + (size_t)row * 256 + c);
      float s = x[0] + x[1] + x[2] + x[3];
      float s2 = x[0]*x[0] + x[1]*x[1] + x[2]*x[2] + x[3]*x[3];
#pragma unroll
      for (int off = 32; off; off >>= 1) { s += __shfl_xor(s, off); s2 += __shfl_xor(s2, off); }
      float mean = s * (1.f / 256.f);
      float rstd = rsqrtf(s2 * (1.f / 256.f) - mean * mean + 1e-5f);
      f32x4 y;
#pragma unroll
      for (int j = 0; j < 4; ++j) y[j] = (x[j] - mean) * rstd * g[c + j] + bvv[c + j];
      *(f32x4*)(nl + r * 257 + c) = y;
    }
    __syncthreads();
    {
      int col = tid & 255, rh = tid >> 8;
      float a6[6] = {0.f, 0.f, 0.f, 0.f, 0.f, 0.f};
      for (int k = 0; k < 256; ++k) {
        float w = p.outN_w1[(size_t)k * 256 + col];
#pragma unroll
        for (int r = 0; r < 6; ++r) a6[r] += nl[(rh * 6 + r) * 257 + k] * w;
      }
#pragma unroll
      for (int r = 0; r < 6; ++r)
        t1f[(rh * 6 + r) * 257 + col] = fmaxf(a6[r] + p.outN_b1[col], 0.f);
    }
    __syncthreads();
    for (int pr = tid; pr < 12 * 13; pr += 512) {
      int il = pr / 13, oc = pr % 13;
      float s = p.outN_b2[oc];
      for (int k = 0; k < 256; ++k) s += t1f[il * 257 + k] * p.outN_w2[k * 13 + oc];
      p.out[((size_t)(bq * NNODE) + i0 + il) * 13 + oc] = s;
    }
  }
}

extern "C" void kernel_launch(void* const* d_in, const int* in_sizes, int n_in,
                              void* d_out, int out_size, void* d_ws, size_t ws_size,
                              hipStream_t stream) {
  (void)in_sizes; (void)n_in; (void)out_size; (void)ws_size;
  Params p;
  const float* const* fi = (const float* const*)d_in;
  p.nodes = fi[0]; p.edges = fi[1]; p.conds = (const int*)d_in[2];
  p.inN_w1 = fi[3]; p.inN_b1 = fi[4]; p.inN_w2 = fi[5]; p.inN_b2 = fi[6];
  p.inE_w1 = fi[7]; p.inE_b1 = fi[8]; p.inE_w2 = fi[9]; p.inE_b2 = fi[10];
  p.inC_w1 = fi[11]; p.inC_b1 = fi[12]; p.inC_w2 = fi[13]; p.inC_b2 = fi[14];
  p.qkv_w = fi[15]; p.qkv_b = fi[16]; p.no_w = fi[17]; p.no_b = fi[18];
  p.eo_w = fi[19]; p.eo_b = fi[20];
  p.ln1n_g = fi[21]; p.ln1n_b = fi[22]; p.ln1e_g = fi[23]; p.ln1e_b = fi[24];
  p.mn_w1 = fi[25]; p.mn_b1 = fi[26]; p.mn_w2 = fi[27]; p.mn_b2 = fi[28];
  p.me_w1 = fi[29]; p.me_b1 = fi[30]; p.me_w2 = fi[31]; p.me_b2 = fi[32];
  p.ln2n_g = fi[33]; p.ln2n_b = fi[34]; p.ln2e_g = fi[35]; p.ln2e_b = fi[36];
  p.outN_w1 = fi[37]; p.outN_b1 = fi[38]; p.outN_w2 = fi[39]; p.outN_b2 = fi[40];
  p.outE_w1 = fi[41]; p.outE_b1 = fi[42]; p.outE_w2 = fi[43]; p.outE_b2 = fi[44];
  p.ws = (float*)d_ws; p.out = (float*)d_out;

  k_embedA<<<dim3(132), dim3(512), 0, stream>>>(p);
  k_embedB<<<dim3(104), dim3(512), 0, stream>>>(p);
  for (int l = 0; l < NLAYER; ++l) {
    k_attn<<<dim3(222), dim3(512), 0, stream>>>(p, l);
    k_mlp<<<dim3(200), dim3(512), 0, stream>>>(p, l);
  }
  k_out<<<dim3(104), dim3(512), 0, stream>>>(p);
}